// Round 1
// baseline (804.866 us; speedup 1.0000x reference)
//
#include <hip/hip_runtime.h>

// Problem constants
#define B_ 256
#define L_ 196
#define C_ 768
#define K_ 2048
#define BL_ 50176  // B_*L_

typedef __attribute__((ext_vector_type(8))) short bf16x8;
typedef __attribute__((ext_vector_type(4))) float f32x4;

typedef const __attribute__((address_space(1))) void gas_void;
typedef __attribute__((address_space(3))) void las_void;

__device__ __forceinline__ unsigned short f2bf(float f) {
  unsigned u = __builtin_bit_cast(unsigned, f);
  u = u + 0x7FFFu + ((u >> 16) & 1u);  // RNE, no NaN inputs
  return (unsigned short)(u >> 16);
}

// monotone map: float bits -> unsigned with total order (handles negatives)
__device__ __forceinline__ unsigned fmono(float f) {
  unsigned u = __builtin_bit_cast(unsigned, f);
  return u ^ ((unsigned)((int)u >> 31) | 0x80000000u);
}

// ---------------------------------------------------------------------------
// Kernel P: per-code precompute: cbb bf16 [K][C], norms64/32, ac.
// ---------------------------------------------------------------------------
__global__ __launch_bounds__(256) void precompute_kernel(
    const float* __restrict__ cb, const float* __restrict__ attw,
    unsigned short* __restrict__ cbb, double* __restrict__ norms64,
    float* __restrict__ norms32, float* __restrict__ ac) {
  int wave = threadIdx.x >> 6;
  int lane = threadIdx.x & 63;
  int k = blockIdx.x * 4 + wave;
  const float* row = cb + (size_t)k * C_;
  double n = 0.0, a = 0.0;
  for (int c = lane; c < C_; c += 64) {
    float v = row[c];
    cbb[(size_t)k * C_ + c] = f2bf(v);
    n = fma((double)v, (double)v, n);
    a = fma((double)v, (double)attw[c * 3 + 1], a);
  }
  for (int off = 32; off > 0; off >>= 1) {
    n += __shfl_down(n, off);
    a += __shfl_down(a, off);
  }
  if (lane == 0) {
    norms64[k] = n;
    norms32[k] = (float)n;
    ac[k] = (a > 0.0) ? (float)a : 0.0f;
  }
}

// ---------------------------------------------------------------------------
// Kernel X: convert in_feas f32 -> bf16 xb [BL][C]. 9633792 float4 groups.
// ---------------------------------------------------------------------------
__global__ __launch_bounds__(256) void convert_kernel(
    const float* __restrict__ x, unsigned short* __restrict__ xb) {
  int i = blockIdx.x * 256 + threadIdx.x;  // exact: 37632*256 = BL_*C_/4
  float4 v = ((const float4*)x)[i];
  uint2 w;
  w.x = (unsigned)f2bf(v.x) | ((unsigned)f2bf(v.y) << 16);
  w.y = (unsigned)f2bf(v.z) | ((unsigned)f2bf(v.w) << 16);
  ((uint2*)xb)[i] = w;
}

// ---------------------------------------------------------------------------
// Phase 1 (v2): 256x256 tile, BK=64, 512 threads = 8 waves (2M x 4N),
// wave tile 128x64 (acc[8][4]).  Double-buffered LDS (2 x 64 KB) with
// 1-ahead global_load_lds staging issued BEFORE the compute of the current
// tile; one __syncthreads per K-step (its implicit vmcnt(0) drain is the
// pipeline wait).  XOR slot swizzle applied to the SOURCE address (deposit
// stays lane-contiguous as global_load_lds requires).  XCD-pinned grid:
// nblk = bid & 7 so each XCD owns one 256-code panel (L2-resident) and all
// XCDs sweep xb in lockstep (L3-resident).
// Epilogue: per-wave top-3 per token over its 64-code column group ->
// 12 candidate keys per token per block into ws_cand[tok][96] (layout
// nblk*12 + wn*3 + j; phase2 is layout-agnostic, keys carry the code).
// ---------------------------------------------------------------------------
__global__ __launch_bounds__(512, 2) void phase1_kernel(
    const unsigned short* __restrict__ xb,
    const unsigned short* __restrict__ cbb,
    const float* __restrict__ norms32, unsigned* __restrict__ ws_cand) {
  __shared__ unsigned short As[2][256 * 64];  // 32 KB per buffer
  __shared__ unsigned short Bs[2][256 * 64];
  __shared__ float norms_s[256];
  __shared__ unsigned cands_s[256][12];

  int tid = threadIdx.x;
  int bid = blockIdx.x;
  int nblk = bid & 7;   // XCD-pinned code panel (1568 = 8 * 196 exactly)
  int mblk = bid >> 3;  // token tile
  size_t row0 = (size_t)mblk * 256;
  int code0 = nblk * 256;

  int w = tid >> 6, l = tid & 63;
  int wm = w >> 2, wn = w & 3;  // 2 x 4 wave grid
  int col16 = l & 15, quad = l >> 4;

  if (tid < 256) norms_s[tid] = norms32[code0 + tid];

  // staging geometry: chunk c = i*512 + tid -> LDS byte c*16.
  // row = c>>3 = i*64 + (tid>>3); slotpos = c&7 = tid&7;
  // source slot is XOR-swizzled: slotraw = slotpos ^ (row&7) (i*64%8==0).
  int crow = tid >> 3;
  int slotraw = (tid & 7) ^ (crow & 7);
  size_t off0 = (size_t)crow * C_ + (size_t)slotraw * 8;
  const unsigned short* abase = xb + row0 * C_ + off0;
  const unsigned short* bbase = cbb + (size_t)code0 * C_ + off0;
  char* alds = (char*)&As[0][0] + w * 1024;  // + buf*32768 + i*8192 (+l*16 HW)
  char* blds = (char*)&Bs[0][0] + w * 1024;

  auto stage = [&](int kt, int buf) {
    const unsigned short* a_ = abase + kt * 64;
    const unsigned short* b_ = bbase + kt * 64;
    char* al_ = alds + buf * 32768;
    char* bl_ = blds + buf * 32768;
#pragma unroll
    for (int i = 0; i < 4; ++i) {
      __builtin_amdgcn_global_load_lds((gas_void*)(a_ + (size_t)i * 64 * C_),
                                       (las_void*)(al_ + i * 8192), 16, 0, 0);
      __builtin_amdgcn_global_load_lds((gas_void*)(b_ + (size_t)i * 64 * C_),
                                       (las_void*)(bl_ + i * 8192), 16, 0, 0);
    }
  };

  f32x4 acc[8][4];
#pragma unroll
  for (int mt = 0; mt < 8; ++mt)
#pragma unroll
    for (int nt = 0; nt < 4; ++nt) acc[mt][nt] = (f32x4){0.f, 0.f, 0.f, 0.f};

  stage(0, 0);
  __syncthreads();  // drains prologue stage

  for (int kt = 0; kt < 12; ++kt) {
    int buf = kt & 1;
    if (kt < 11) stage(kt + 1, buf ^ 1);  // overlapped with compute below
    const char* Ab = (const char*)&As[buf][0];
    const char* Bb = (const char*)&Bs[buf][0];
#pragma unroll
    for (int ks = 0; ks < 2; ++ks) {
      int sl = (ks * 4 + quad) ^ (col16 & 7);  // row&7 == col16&7 for all rows
      bf16x8 af[8], bf[4];
#pragma unroll
      for (int mt = 0; mt < 8; ++mt) {
        int row = wm * 128 + mt * 16 + col16;
        af[mt] = *(const bf16x8*)(Ab + row * 128 + sl * 16);
      }
#pragma unroll
      for (int nt = 0; nt < 4; ++nt) {
        int row = wn * 64 + nt * 16 + col16;
        bf[nt] = *(const bf16x8*)(Bb + row * 128 + sl * 16);
      }
#pragma unroll
      for (int mt = 0; mt < 8; ++mt)
#pragma unroll
        for (int nt = 0; nt < 4; ++nt)
          acc[mt][nt] = __builtin_amdgcn_mfma_f32_16x16x32_bf16(
              af[mt], bf[nt], acc[mt][nt], 0, 0, 0);
    }
    __syncthreads();  // implicit vmcnt(0): next-tile deposits complete
  }

  // epilogue: top-3 per token within this wave's 64 codes
#pragma unroll
  for (int mt = 0; mt < 8; ++mt) {
#pragma unroll
    for (int r = 0; r < 4; ++r) {
      unsigned keys[4];
#pragma unroll
      for (int nt = 0; nt < 4; ++nt) {
        int codel = wn * 64 + nt * 16 + col16;
        float d = fmaf(-2.0f, acc[mt][nt][r], norms_s[codel]);
        keys[nt] = (fmono(d) & 0xFFFFF800u) | (unsigned)(code0 + codel);
      }
      unsigned win[3];
#pragma unroll
      for (int rnd = 0; rnd < 3; ++rnd) {
        unsigned mn = min(min(keys[0], keys[1]), min(keys[2], keys[3]));
        mn = min(mn, (unsigned)__shfl_xor((int)mn, 1));
        mn = min(mn, (unsigned)__shfl_xor((int)mn, 2));
        mn = min(mn, (unsigned)__shfl_xor((int)mn, 4));
        mn = min(mn, (unsigned)__shfl_xor((int)mn, 8));
        win[rnd] = mn;
#pragma unroll
        for (int nt = 0; nt < 4; ++nt)
          if (keys[nt] == mn) keys[nt] = 0xFFFFFFFFu;
      }
      if (col16 == 0) {
        int t = wm * 128 + mt * 16 + quad * 4 + r;
        cands_s[t][wn * 3 + 0] = win[0];
        cands_s[t][wn * 3 + 1] = win[1];
        cands_s[t][wn * 3 + 2] = win[2];
      }
    }
  }
  __syncthreads();
  for (int i = tid; i < 256 * 12; i += 512) {
    int t = i / 12;
    int j = i - t * 12;
    ws_cand[(row0 + t) * 96 + nblk * 12 + j] = cands_s[t][j];
  }
}

// ---------------------------------------------------------------------------
// Phase 2: per token, top-6 of 96 approx keys -> exact f64 rescore -> idx.
// ---------------------------------------------------------------------------
__global__ __launch_bounds__(256) void phase2_kernel(
    const float* __restrict__ x, const float* __restrict__ cb,
    const unsigned* __restrict__ ws_cand, const double* __restrict__ norms64,
    int* __restrict__ out_idx) {
  __shared__ unsigned cl[32][100];  // pad 96->100 (bank spread)
  __shared__ int rcode[32][6];
  __shared__ double rd[32][6];
  int tid = threadIdx.x;
  size_t tok0 = (size_t)blockIdx.x * 32;

  for (int i = tid; i < 32 * 96; i += 256) {
    int t = i / 96;
    int s = i - t * 96;
    cl[t][s] = ws_cand[tok0 * 96 + i];
  }
  __syncthreads();

  if (tid < 32) {
    unsigned best[6];
#pragma unroll
    for (int j = 0; j < 6; ++j) best[j] = 0xFFFFFFFFu;
    for (int s = 0; s < 96; ++s) {
      unsigned v = cl[tid][s];
      if (v < best[5]) {
        best[5] = v;
#pragma unroll
        for (int j = 5; j > 0; --j) {
          if (best[j] < best[j - 1]) {
            unsigned t = best[j];
            best[j] = best[j - 1];
            best[j - 1] = t;
          }
        }
      }
    }
#pragma unroll
    for (int j = 0; j < 6; ++j) rcode[tid][j] = (int)(best[j] & 0x7FFu);
  }
  __syncthreads();

  if (tid < 192) {
    int t = tid / 6;
    int j = tid - t * 6;
    int code = rcode[t][j];
    const float* xr = x + (tok0 + t) * (size_t)C_;
    const float* cr = cb + (size_t)code * C_;
    double s = 0.0;
    for (int c = 0; c < C_; c += 4) {
      float4 xa = *(const float4*)(xr + c);
      float4 ca = *(const float4*)(cr + c);
      s = fma((double)xa.x, (double)ca.x, s);
      s = fma((double)xa.y, (double)ca.y, s);
      s = fma((double)xa.z, (double)ca.z, s);
      s = fma((double)xa.w, (double)ca.w, s);
    }
    rd[t][j] = fma(-2.0, s, norms64[code]);
  }
  __syncthreads();

  if (tid < 32) {
    double bv = rd[tid][0];
    int bi = rcode[tid][0];
#pragma unroll
    for (int j = 1; j < 6; ++j) {
      double v = rd[tid][j];
      int i0 = rcode[tid][j];
      if (v < bv || (v == bv && i0 < bi)) {
        bv = v;
        bi = i0;
      }
    }
    out_idx[tok0 + tid] = bi;
  }
}

// ---------------------------------------------------------------------------
// Fallback argmin (round-2 kernel) if ws_size is too small for phase 1/2.
// ---------------------------------------------------------------------------
#define APAD 776
__global__ __launch_bounds__(256, 2) void argmin_fallback(
    const float* __restrict__ x, const float* __restrict__ cb,
    const unsigned short* __restrict__ cbb,
    const double* __restrict__ norms64, const float* __restrict__ norms32,
    int* __restrict__ out_idx) {
  __shared__ unsigned short Asf[32 * APAD];
  __shared__ float norms_s[K_];
  __shared__ unsigned int cands[32][48];
  __shared__ int rcode[32][6];
  __shared__ double rd[32][6];

  int tid = threadIdx.x;
  size_t tok0 = (size_t)blockIdx.x * 32;

  for (int i = tid; i < K_; i += 256) norms_s[i] = norms32[i];

  const float4* xin = (const float4*)(x + tok0 * C_);
  for (int i = tid; i < 32 * 192; i += 256) {
    int tok = i / 192;
    int c4 = i - tok * 192;
    float4 v = xin[i];
    uint2 w;
    w.x = (unsigned)f2bf(v.x) | ((unsigned)f2bf(v.y) << 16);
    w.y = (unsigned)f2bf(v.z) | ((unsigned)f2bf(v.w) << 16);
    *(uint2*)&Asf[tok * APAD + c4 * 4] = w;
  }
  __syncthreads();

  int wv = tid >> 6;
  int lane = tid & 63;
  int col = lane & 15;
  int quad = lane >> 4;

  const unsigned short* a0p = &Asf[(col)*APAD + quad * 8];
  const unsigned short* a1p = &Asf[(16 + col) * APAD + quad * 8];

  for (int chunk = 0; chunk < 4; ++chunk) {
    int code0 = chunk * 512 + wv * 128 + col;
    const unsigned short* bbase = cbb + (size_t)code0 * C_ + quad * 8;

    f32x4 acc[2][8];
#pragma unroll
    for (int m = 0; m < 2; ++m)
#pragma unroll
      for (int n = 0; n < 8; ++n) acc[m][n] = (f32x4){0.f, 0.f, 0.f, 0.f};

    bf16x8 ca0 = *(const bf16x8*)(a0p);
    bf16x8 ca1 = *(const bf16x8*)(a1p);
    bf16x8 cbf[8];
#pragma unroll
    for (int n = 0; n < 8; ++n)
      cbf[n] = *(const bf16x8*)(bbase + (size_t)n * 16 * C_);

    for (int ks = 0; ks < 24; ++ks) {
      bf16x8 na0, na1, nbf[8];
      if (ks < 23) {
        int k1 = (ks + 1) * 32;
        na0 = *(const bf16x8*)(a0p + k1);
        na1 = *(const bf16x8*)(a1p + k1);
#pragma unroll
        for (int n = 0; n < 8; ++n)
          nbf[n] = *(const bf16x8*)(bbase + (size_t)n * 16 * C_ + k1);
      }
#pragma unroll
      for (int n = 0; n < 8; ++n) {
        acc[0][n] = __builtin_amdgcn_mfma_f32_16x16x32_bf16(ca0, cbf[n],
                                                            acc[0][n], 0, 0, 0);
        acc[1][n] = __builtin_amdgcn_mfma_f32_16x16x32_bf16(ca1, cbf[n],
                                                            acc[1][n], 0, 0, 0);
      }
      if (ks < 23) {
        ca0 = na0;
        ca1 = na1;
#pragma unroll
        for (int n = 0; n < 8; ++n) cbf[n] = nbf[n];
      }
    }

#pragma unroll
    for (int m = 0; m < 2; ++m) {
#pragma unroll
      for (int r = 0; r < 4; ++r) {
        unsigned keys[8];
#pragma unroll
        for (int n = 0; n < 8; ++n) {
          int code = code0 + n * 16;
          float d = fmaf(-2.0f, acc[m][n][r], norms_s[code]);
          keys[n] = (fmono(d) & 0xFFFFF800u) | (unsigned)code;
        }
        unsigned win[3];
#pragma unroll
        for (int rnd = 0; rnd < 3; ++rnd) {
          unsigned mn = keys[0];
#pragma unroll
          for (int n = 1; n < 8; ++n) mn = min(mn, keys[n]);
          mn = min(mn, (unsigned)__shfl_xor((int)mn, 1));
          mn = min(mn, (unsigned)__shfl_xor((int)mn, 2));
          mn = min(mn, (unsigned)__shfl_xor((int)mn, 4));
          mn = min(mn, (unsigned)__shfl_xor((int)mn, 8));
          win[rnd] = mn;
#pragma unroll
          for (int n = 0; n < 8; ++n)
            if (keys[n] == mn) keys[n] = 0xFFFFFFFFu;
        }
        if (col == 0) {
          int token = m * 16 + quad * 4 + r;
          unsigned* cp = &cands[token][chunk * 12 + wv * 3];
          cp[0] = win[0];
          cp[1] = win[1];
          cp[2] = win[2];
        }
      }
    }
  }
  __syncthreads();

  if (tid < 32) {
    unsigned best[6];
#pragma unroll
    for (int j = 0; j < 6; ++j) best[j] = 0xFFFFFFFFu;
    for (int s = 0; s < 48; ++s) {
      unsigned v = cands[tid][s];
      if (v < best[5]) {
        best[5] = v;
#pragma unroll
        for (int j = 5; j > 0; --j) {
          if (best[j] < best[j - 1]) {
            unsigned t = best[j];
            best[j] = best[j - 1];
            best[j - 1] = t;
          }
        }
      }
    }
#pragma unroll
    for (int j = 0; j < 6; ++j) rcode[tid][j] = (int)(best[j] & 0x7FFu);
  }
  __syncthreads();

  if (tid < 192) {
    int t = tid / 6;
    int j = tid - t * 6;
    int code = rcode[t][j];
    const float* xr = x + (tok0 + t) * (size_t)C_;
    const float* cr = cb + (size_t)code * C_;
    double s = 0.0;
    for (int c = 0; c < C_; c += 4) {
      float4 xa = *(const float4*)(xr + c);
      float4 ca = *(const float4*)(cr + c);
      s = fma((double)xa.x, (double)ca.x, s);
      s = fma((double)xa.y, (double)ca.y, s);
      s = fma((double)xa.z, (double)ca.z, s);
      s = fma((double)xa.w, (double)ca.w, s);
    }
    rd[t][j] = fma(-2.0, s, norms64[code]);
  }
  __syncthreads();

  if (tid < 32) {
    double bv = rd[tid][0];
    int bi = rcode[tid][0];
#pragma unroll
    for (int j = 1; j < 6; ++j) {
      double v = rd[tid][j];
      int i0 = rcode[tid][j];
      if (v < bv || (v == bv && i0 < bi)) {
        bv = v;
        bi = i0;
      }
    }
    out_idx[tok0 + tid] = bi;
  }
}

// ---------------------------------------------------------------------------
// Kernel E: per-batch softmax over att = ac[idx[l]] + fused output.
// ---------------------------------------------------------------------------
__global__ __launch_bounds__(256) void epilogue_kernel(
    const float* __restrict__ x, const float* __restrict__ cb,
    const float* __restrict__ ac, const int* __restrict__ idx,
    float* __restrict__ out, float* __restrict__ out_idx) {
  __shared__ float att[256];
  __shared__ float red[256];
  __shared__ int ids[L_];
  int b = blockIdx.x;
  int tid = threadIdx.x;

  float a = -1e30f;
  int myid = 0;
  if (tid < L_) {
    myid = idx[b * L_ + tid];
    ids[tid] = myid;
    a = ac[myid];
  }
  att[tid] = a;
  red[tid] = a;
  __syncthreads();
  for (int s = 128; s > 0; s >>= 1) {
    if (tid < s) red[tid] = fmaxf(red[tid], red[tid + s]);
    __syncthreads();
  }
  float m = red[0];
  __syncthreads();
  float e = (tid < L_) ? expf(att[tid] - m) : 0.0f;
  red[tid] = e;
  __syncthreads();
  for (int s = 128; s > 0; s >>= 1) {
    if (tid < s) red[tid] += red[tid + s];
    __syncthreads();
  }
  float sum = red[0];
  __syncthreads();
  att[tid] = e / sum;
  __syncthreads();

  const float4* xin = (const float4*)(x + (size_t)b * L_ * C_);
  float4* o = (float4*)(out + (size_t)b * L_ * C_);
  for (int i = tid; i < L_ * (C_ / 4); i += 256) {
    int l = i / (C_ / 4);
    int c4 = i - l * (C_ / 4);
    const float4* crow = (const float4*)(cb + (size_t)ids[l] * C_);
    float4 xv = xin[i];
    float4 cv = crow[c4];
    float mk = att[l];
    float4 ov;
    ov.x = cv.x + xv.x * mk;
    ov.y = cv.y + xv.y * mk;
    ov.z = cv.z + xv.z * mk;
    ov.w = cv.w + xv.w * mk;
    o[i] = ov;
  }
  if (tid < L_) out_idx[b * L_ + tid] = (float)ids[tid];
}

// ---------------------------------------------------------------------------
extern "C" void kernel_launch(void* const* d_in, const int* in_sizes, int n_in,
                              void* d_out, int out_size, void* d_ws,
                              size_t ws_size, hipStream_t stream) {
  const float* in_feas = (const float*)d_in[0];   // [B,L,C] f32
  const float* cb = (const float*)d_in[1];        // [K,C]   f32
  const float* attw = (const float*)d_in[2];      // [1,C,3] f32

  // workspace layout
  char* ws = (char*)d_ws;
  size_t off = 0;
  unsigned short* cbb = (unsigned short*)(ws + off); off += 3145728;
  double* norms64 = (double*)(ws + off);           off += 16384;
  float* norms32 = (float*)(ws + off);             off += 8192;
  float* ac = (float*)(ws + off);                  off += 8192;
  int* idx = (int*)(ws + off);                     off += 200704;
  size_t base = off;                                // 3,379,200
  unsigned short* xb = (unsigned short*)(ws + off); off += (size_t)BL_ * C_ * 2;
  unsigned* ws_cand = (unsigned*)(ws + off);        off += (size_t)BL_ * 96 * 4;
  size_t need_full = off;                           // ~99.7 MB

  float* out = (float*)d_out;                      // out_feas [B,L,C]
  float* out_idx = out + (size_t)B_ * L_ * C_;     // idx map as float [B,H,W]

  precompute_kernel<<<K_ / 4, 256, 0, stream>>>(cb, attw, cbb, norms64,
                                                norms32, ac);
  if (ws_size >= need_full) {
    convert_kernel<<<BL_ * C_ / 4 / 256, 256, 0, stream>>>(in_feas, xb);
    // 1568 blocks = (BL/256) * (K/256) = 196 * 8; nblk = bid&7 (XCD-pinned)
    phase1_kernel<<<dim3((BL_ / 256) * (K_ / 256)), 512, 0, stream>>>(
        xb, cbb, norms32, ws_cand);
    phase2_kernel<<<BL_ / 32, 256, 0, stream>>>(in_feas, cb, ws_cand, norms64,
                                                idx);
  } else {
    argmin_fallback<<<BL_ / 32, 256, 0, stream>>>(in_feas, cb, cbb, norms64,
                                                  norms32, idx);
  }
  epilogue_kernel<<<B_, 256, 0, stream>>>(in_feas, cb, ac, idx, out, out_idx);
  (void)base;
}

// Round 3
// 796.381 us; speedup vs baseline: 1.0107x; 1.0107x over previous
//
#include <hip/hip_runtime.h>

// Problem constants
#define B_ 256
#define L_ 196
#define C_ 768
#define K_ 2048
#define BL_ 50176  // B_*L_

typedef __attribute__((ext_vector_type(8))) short bf16x8;
typedef __attribute__((ext_vector_type(4))) float f32x4;

typedef const __attribute__((address_space(1))) void gas_void;
typedef __attribute__((address_space(3))) void las_void;

__device__ __forceinline__ unsigned short f2bf(float f) {
  unsigned u = __builtin_bit_cast(unsigned, f);
  u = u + 0x7FFFu + ((u >> 16) & 1u);  // RNE, no NaN inputs
  return (unsigned short)(u >> 16);
}

// monotone map: float bits -> unsigned with total order (handles negatives)
__device__ __forceinline__ unsigned fmono(float f) {
  unsigned u = __builtin_bit_cast(unsigned, f);
  return u ^ ((unsigned)((int)u >> 31) | 0x80000000u);
}

// ---------------------------------------------------------------------------
// Kernel P: per-code precompute: cbb bf16 [K][C], norms64/32, ac.
// ---------------------------------------------------------------------------
__global__ __launch_bounds__(256) void precompute_kernel(
    const float* __restrict__ cb, const float* __restrict__ attw,
    unsigned short* __restrict__ cbb, double* __restrict__ norms64,
    float* __restrict__ norms32, float* __restrict__ ac) {
  int wave = threadIdx.x >> 6;
  int lane = threadIdx.x & 63;
  int k = blockIdx.x * 4 + wave;
  const float* row = cb + (size_t)k * C_;
  double n = 0.0, a = 0.0;
  for (int c = lane; c < C_; c += 64) {
    float v = row[c];
    cbb[(size_t)k * C_ + c] = f2bf(v);
    n = fma((double)v, (double)v, n);
    a = fma((double)v, (double)attw[c * 3 + 1], a);
  }
  for (int off = 32; off > 0; off >>= 1) {
    n += __shfl_down(n, off);
    a += __shfl_down(a, off);
  }
  if (lane == 0) {
    norms64[k] = n;
    norms32[k] = (float)n;
    ac[k] = (a > 0.0) ? (float)a : 0.0f;
  }
}

// ---------------------------------------------------------------------------
// Kernel X: convert in_feas f32 -> bf16 xb [BL][C]. 9633792 float4 groups.
// ---------------------------------------------------------------------------
__global__ __launch_bounds__(256) void convert_kernel(
    const float* __restrict__ x, unsigned short* __restrict__ xb) {
  int i = blockIdx.x * 256 + threadIdx.x;  // exact: 37632*256 = BL_*C_/4
  float4 v = ((const float4*)x)[i];
  uint2 w;
  w.x = (unsigned)f2bf(v.x) | ((unsigned)f2bf(v.y) << 16);
  w.y = (unsigned)f2bf(v.z) | ((unsigned)f2bf(v.w) << 16);
  ((uint2*)xb)[i] = w;
}

// ---------------------------------------------------------------------------
// Phase 1 (v3): 256x256 tile, BK=64, 512 threads = 8 waves (2M x 4N),
// 8-phase pipelined schedule (T3+T4+T5 port, m201-style):
//   - per K-tile, 4 phases walking C-quadrants (A0B0)->(A0B1)->(A1B1)->(A1B0)
//   - one 16KB half-tile staged per phase via 2x global_load_lds/thread
//   - ONE counted s_waitcnt vmcnt(6) per K-tile (3 half-tiles in flight),
//     never vmcnt(0) in steady state (tail kt=10 drains to 0)
//   - raw s_barrier + lgkmcnt(0) + setprio(1) around each 16-MFMA cluster
// Staging cadence (race-free by construction; vmcnt retires in issue order):
//   P0 stages next-Ktile B0 -> other buf; P1/P2/P3 stage Ktile+2 A0/B1/A1
//   into the CURRENT buf, each only after that region's last read was sealed
//   by the preceding phase's closing barrier.
// Block mapping: the 8 consecutively-dispatched blocks on one XCD share the
// SAME token tile (mblk) across the 8 code panels -> 384KB xb tile fetched
// once into that XCD's L2, reused 8x; cbb (3MB) L2-resident.
// Epilogue: per-wave top-3 per token over its 64 codes -> 12 cands/token.
// ---------------------------------------------------------------------------
__global__ __launch_bounds__(512, 2) void phase1_kernel(
    const unsigned short* __restrict__ xb,
    const unsigned short* __restrict__ cbb,
    const float* __restrict__ norms32, unsigned* __restrict__ ws_cand) {
  // [buf][op(0=A,1=B)][half][128*64] bf16 = 128 KB
  __shared__ unsigned short lds[2][2][2][128 * 64];
  __shared__ float norms_s[256];
  __shared__ unsigned cands_s[256][12];

  int tid = threadIdx.x;
  int bid = blockIdx.x;
  // token-tile-shared-per-XCD mapping (see header comment)
  int x8 = bid & 7, m = bid >> 3;
  int mblk, nblk;
  if (m < 192) {
    mblk = (m & ~7) | x8;  // 8 consecutive blocks on an XCD share mblk
    nblk = m & 7;
  } else {
    mblk = m;  // 192..195
    nblk = x8;
  }
  size_t row0 = (size_t)mblk * 256;
  int code0 = nblk * 256;

  int wv = tid >> 6, l = tid & 63;
  int wm = wv >> 2, wn = wv & 3;  // 2 x 4 wave grid
  int col16 = l & 15, quad = l >> 4;

  if (tid < 256) norms_s[tid] = norms32[code0 + tid];

  // staging geometry: half-tile = 128 rows x 64 cols bf16 = 16 KB.
  // chunk c = i*512 + tid -> LDS byte c*16; row = i*64 + (tid>>3),
  // slotpos = tid&7; source slot XOR-swizzled: slotraw = slotpos ^ (row&7).
  int slotraw = (tid & 7) ^ ((tid >> 3) & 7);
  const unsigned short* abase = xb + (row0 + (tid >> 3)) * (size_t)C_ +
                                (size_t)slotraw * 8;
  const unsigned short* bbase = cbb + ((size_t)code0 + (tid >> 3)) * C_ +
                                (size_t)slotraw * 8;

  auto stageA = [&](int kt, int half, int buf) {
    const unsigned short* s =
        abase + (size_t)half * 128 * C_ + (size_t)kt * 64;
    char* d = (char*)&lds[buf][0][half][0] + wv * 1024;
    __builtin_amdgcn_global_load_lds((gas_void*)s, (las_void*)d, 16, 0, 0);
    __builtin_amdgcn_global_load_lds((gas_void*)(s + (size_t)64 * C_),
                                     (las_void*)(d + 8192), 16, 0, 0);
  };
  auto stageB = [&](int kt, int half, int buf) {
    const unsigned short* s =
        bbase + (size_t)half * 128 * C_ + (size_t)kt * 64;
    char* d = (char*)&lds[buf][1][half][0] + wv * 1024;
    __builtin_amdgcn_global_load_lds((gas_void*)s, (las_void*)d, 16, 0, 0);
    __builtin_amdgcn_global_load_lds((gas_void*)(s + (size_t)64 * C_),
                                     (las_void*)(d + 8192), 16, 0, 0);
  };

  f32x4 acc[2][2][4][2];  // [mh][nh][mt][nt]
#pragma unroll
  for (int mh = 0; mh < 2; ++mh)
#pragma unroll
    for (int nh = 0; nh < 2; ++nh)
#pragma unroll
      for (int mt = 0; mt < 4; ++mt)
#pragma unroll
        for (int nt = 0; nt < 2; ++nt)
          acc[mh][nh][mt][nt] = (f32x4){0.f, 0.f, 0.f, 0.f};

  bf16x8 af[4][2], bfr[2][2];

#define LOADA(P)                                                            \
  _Pragma("unroll") for (int mt = 0; mt < 4; ++mt)                          \
      _Pragma("unroll") for (int ks = 0; ks < 2; ++ks) af[mt][ks] =         \
      *(const bf16x8*)((P) + (wm * 64 + mt * 16 + col16) * 128 +            \
                       (((ks * 4 + quad) ^ (col16 & 7)) * 16));

#define LOADB(P)                                                            \
  _Pragma("unroll") for (int nt = 0; nt < 2; ++nt)                          \
      _Pragma("unroll") for (int ks = 0; ks < 2; ++ks) bfr[nt][ks] =        \
      *(const bf16x8*)((P) + (wn * 32 + nt * 16 + col16) * 128 +            \
                       (((ks * 4 + quad) ^ (col16 & 7)) * 16));

#define MFMA_PHASE(mh, nh)                                                  \
  __builtin_amdgcn_s_barrier();                                             \
  asm volatile("s_waitcnt lgkmcnt(0)" ::: "memory");                        \
  __builtin_amdgcn_s_setprio(1);                                            \
  _Pragma("unroll") for (int mt = 0; mt < 4; ++mt)                          \
      _Pragma("unroll") for (int nt = 0; nt < 2; ++nt)                      \
          _Pragma("unroll") for (int ks = 0; ks < 2; ++ks) acc[mh][nh][mt]  \
      [nt] = __builtin_amdgcn_mfma_f32_16x16x32_bf16(                       \
          af[mt][ks], bfr[nt][ks], acc[mh][nh][mt][nt], 0, 0, 0);           \
  __builtin_amdgcn_s_setprio(0);                                            \
  __builtin_amdgcn_s_barrier();

  // Prologue: emulate loop cadence for K-tiles 0 and 1.
  // Issue order: t0-A0, t0-B1, t0-A1, t0-B0, t1-A0, t1-B1, t1-A1 (14 loads).
  stageA(0, 0, 0);
  stageB(0, 1, 0);
  stageA(0, 1, 0);
  stageB(0, 0, 0);
  stageA(1, 0, 1);
  stageB(1, 1, 1);
  stageA(1, 1, 1);
  asm volatile("s_waitcnt vmcnt(6)" ::: "memory");  // t0's 4 halves retired
  __builtin_amdgcn_s_barrier();

  for (int kt = 0; kt < 12; ++kt) {
    int buf = kt & 1;
    const char* A0p = (const char*)&lds[buf][0][0][0];
    const char* A1p = (const char*)&lds[buf][0][1][0];
    const char* B0p = (const char*)&lds[buf][1][0][0];
    const char* B1p = (const char*)&lds[buf][1][1][0];

    // ---- P0: quadrant (A0,B0) ----
    if (kt + 1 < 12) stageB(kt + 1, 0, buf ^ 1);
    LOADA(A0p);
    LOADB(B0p);
    MFMA_PHASE(0, 0);
    // ---- P1: quadrant (A0,B1) ----  (A0 reads sealed by P0's close barrier)
    if (kt + 2 < 12) stageA(kt + 2, 0, buf);
    LOADB(B1p);
    MFMA_PHASE(0, 1);
    // ---- P2: quadrant (A1,B1) ----  (B1 reads sealed by P1's close barrier)
    if (kt + 2 < 12) stageB(kt + 2, 1, buf);
    LOADA(A1p);
    MFMA_PHASE(1, 1);
    // ---- P3: quadrant (A1,B0) ----  (A1 reads sealed by P2's close barrier)
    if (kt + 2 < 12) stageA(kt + 2, 1, buf);
    if (kt <= 9) {
      asm volatile("s_waitcnt vmcnt(6)" ::: "memory");  // next K-tile ready
    } else if (kt == 10) {
      asm volatile("s_waitcnt vmcnt(0)" ::: "memory");  // tail drain
    }
    LOADB(B0p);
    MFMA_PHASE(1, 0);
  }

#undef LOADA
#undef LOADB
#undef MFMA_PHASE

  // epilogue: top-3 per token within this wave's 64 codes (4x16 over nh,nt)
#pragma unroll
  for (int mh = 0; mh < 2; ++mh) {
#pragma unroll
    for (int mt = 0; mt < 4; ++mt) {
#pragma unroll
      for (int r = 0; r < 4; ++r) {
        unsigned keys[4];
#pragma unroll
        for (int nh = 0; nh < 2; ++nh)
#pragma unroll
          for (int nt = 0; nt < 2; ++nt) {
            int codel = nh * 128 + wn * 32 + nt * 16 + col16;
            float d = fmaf(-2.0f, acc[mh][nh][mt][nt][r], norms_s[codel]);
            keys[nh * 2 + nt] =
                (fmono(d) & 0xFFFFF800u) | (unsigned)(code0 + codel);
          }
        unsigned win[3];
#pragma unroll
        for (int rnd = 0; rnd < 3; ++rnd) {
          unsigned mn = min(min(keys[0], keys[1]), min(keys[2], keys[3]));
          mn = min(mn, (unsigned)__shfl_xor((int)mn, 1));
          mn = min(mn, (unsigned)__shfl_xor((int)mn, 2));
          mn = min(mn, (unsigned)__shfl_xor((int)mn, 4));
          mn = min(mn, (unsigned)__shfl_xor((int)mn, 8));
          win[rnd] = mn;
#pragma unroll
          for (int nt = 0; nt < 4; ++nt)
            if (keys[nt] == mn) keys[nt] = 0xFFFFFFFFu;
        }
        if (col16 == 0) {
          int t = mh * 128 + wm * 64 + mt * 16 + quad * 4 + r;
          cands_s[t][wn * 3 + 0] = win[0];
          cands_s[t][wn * 3 + 1] = win[1];
          cands_s[t][wn * 3 + 2] = win[2];
        }
      }
    }
  }
  __syncthreads();
  for (int i = tid; i < 256 * 12; i += 512) {
    int t = i / 12;
    int j = i - t * 12;
    ws_cand[(row0 + t) * 96 + nblk * 12 + j] = cands_s[t][j];
  }
}

// ---------------------------------------------------------------------------
// Phase 2: per token, top-6 of 96 approx keys -> exact f64 rescore -> idx.
// ---------------------------------------------------------------------------
__global__ __launch_bounds__(256) void phase2_kernel(
    const float* __restrict__ x, const float* __restrict__ cb,
    const unsigned* __restrict__ ws_cand, const double* __restrict__ norms64,
    int* __restrict__ out_idx) {
  __shared__ unsigned cl[32][100];  // pad 96->100 (bank spread)
  __shared__ int rcode[32][6];
  __shared__ double rd[32][6];
  int tid = threadIdx.x;
  size_t tok0 = (size_t)blockIdx.x * 32;

  for (int i = tid; i < 32 * 96; i += 256) {
    int t = i / 96;
    int s = i - t * 96;
    cl[t][s] = ws_cand[tok0 * 96 + i];
  }
  __syncthreads();

  if (tid < 32) {
    unsigned best[6];
#pragma unroll
    for (int j = 0; j < 6; ++j) best[j] = 0xFFFFFFFFu;
    for (int s = 0; s < 96; ++s) {
      unsigned v = cl[tid][s];
      if (v < best[5]) {
        best[5] = v;
#pragma unroll
        for (int j = 5; j > 0; --j) {
          if (best[j] < best[j - 1]) {
            unsigned t = best[j];
            best[j] = best[j - 1];
            best[j - 1] = t;
          }
        }
      }
    }
#pragma unroll
    for (int j = 0; j < 6; ++j) rcode[tid][j] = (int)(best[j] & 0x7FFu);
  }
  __syncthreads();

  if (tid < 192) {
    int t = tid / 6;
    int j = tid - t * 6;
    int code = rcode[t][j];
    const float* xr = x + (tok0 + t) * (size_t)C_;
    const float* cr = cb + (size_t)code * C_;
    double s = 0.0;
    for (int c = 0; c < C_; c += 4) {
      float4 xa = *(const float4*)(xr + c);
      float4 ca = *(const float4*)(cr + c);
      s = fma((double)xa.x, (double)ca.x, s);
      s = fma((double)xa.y, (double)ca.y, s);
      s = fma((double)xa.z, (double)ca.z, s);
      s = fma((double)xa.w, (double)ca.w, s);
    }
    rd[t][j] = fma(-2.0, s, norms64[code]);
  }
  __syncthreads();

  if (tid < 32) {
    double bv = rd[tid][0];
    int bi = rcode[tid][0];
#pragma unroll
    for (int j = 1; j < 6; ++j) {
      double v = rd[tid][j];
      int i0 = rcode[tid][j];
      if (v < bv || (v == bv && i0 < bi)) {
        bv = v;
        bi = i0;
      }
    }
    out_idx[tok0 + tid] = bi;
  }
}

// ---------------------------------------------------------------------------
// Fallback argmin (round-2 kernel) if ws_size is too small for phase 1/2.
// ---------------------------------------------------------------------------
#define APAD 776
__global__ __launch_bounds__(256, 2) void argmin_fallback(
    const float* __restrict__ x, const float* __restrict__ cb,
    const unsigned short* __restrict__ cbb,
    const double* __restrict__ norms64, const float* __restrict__ norms32,
    int* __restrict__ out_idx) {
  __shared__ unsigned short Asf[32 * APAD];
  __shared__ float norms_s[K_];
  __shared__ unsigned int cands[32][48];
  __shared__ int rcode[32][6];
  __shared__ double rd[32][6];

  int tid = threadIdx.x;
  size_t tok0 = (size_t)blockIdx.x * 32;

  for (int i = tid; i < K_; i += 256) norms_s[i] = norms32[i];

  const float4* xin = (const float4*)(x + tok0 * C_);
  for (int i = tid; i < 32 * 192; i += 256) {
    int tok = i / 192;
    int c4 = i - tok * 192;
    float4 v = xin[i];
    uint2 w;
    w.x = (unsigned)f2bf(v.x) | ((unsigned)f2bf(v.y) << 16);
    w.y = (unsigned)f2bf(v.z) | ((unsigned)f2bf(v.w) << 16);
    *(uint2*)&Asf[tok * APAD + c4 * 4] = w;
  }
  __syncthreads();

  int wv = tid >> 6;
  int lane = tid & 63;
  int col = lane & 15;
  int quad = lane >> 4;

  const unsigned short* a0p = &Asf[(col)*APAD + quad * 8];
  const unsigned short* a1p = &Asf[(16 + col) * APAD + quad * 8];

  for (int chunk = 0; chunk < 4; ++chunk) {
    int code0 = chunk * 512 + wv * 128 + col;
    const unsigned short* bbase = cbb + (size_t)code0 * C_ + quad * 8;

    f32x4 acc[2][8];
#pragma unroll
    for (int m = 0; m < 2; ++m)
#pragma unroll
      for (int n = 0; n < 8; ++n) acc[m][n] = (f32x4){0.f, 0.f, 0.f, 0.f};

    bf16x8 ca0 = *(const bf16x8*)(a0p);
    bf16x8 ca1 = *(const bf16x8*)(a1p);
    bf16x8 cbf[8];
#pragma unroll
    for (int n = 0; n < 8; ++n)
      cbf[n] = *(const bf16x8*)(bbase + (size_t)n * 16 * C_);

    for (int ks = 0; ks < 24; ++ks) {
      bf16x8 na0, na1, nbf[8];
      if (ks < 23) {
        int k1 = (ks + 1) * 32;
        na0 = *(const bf16x8*)(a0p + k1);
        na1 = *(const bf16x8*)(a1p + k1);
#pragma unroll
        for (int n = 0; n < 8; ++n)
          nbf[n] = *(const bf16x8*)(bbase + (size_t)n * 16 * C_ + k1);
      }
#pragma unroll
      for (int n = 0; n < 8; ++n) {
        acc[0][n] = __builtin_amdgcn_mfma_f32_16x16x32_bf16(ca0, cbf[n],
                                                            acc[0][n], 0, 0, 0);
        acc[1][n] = __builtin_amdgcn_mfma_f32_16x16x32_bf16(ca1, cbf[n],
                                                            acc[1][n], 0, 0, 0);
      }
      if (ks < 23) {
        ca0 = na0;
        ca1 = na1;
#pragma unroll
        for (int n = 0; n < 8; ++n) cbf[n] = nbf[n];
      }
    }

#pragma unroll
    for (int m = 0; m < 2; ++m) {
#pragma unroll
      for (int r = 0; r < 4; ++r) {
        unsigned keys[8];
#pragma unroll
        for (int n = 0; n < 8; ++n) {
          int code = code0 + n * 16;
          float d = fmaf(-2.0f, acc[m][n][r], norms_s[code]);
          keys[n] = (fmono(d) & 0xFFFFF800u) | (unsigned)code;
        }
        unsigned win[3];
#pragma unroll
        for (int rnd = 0; rnd < 3; ++rnd) {
          unsigned mn = keys[0];
#pragma unroll
          for (int n = 1; n < 8; ++n) mn = min(mn, keys[n]);
          mn = min(mn, (unsigned)__shfl_xor((int)mn, 1));
          mn = min(mn, (unsigned)__shfl_xor((int)mn, 2));
          mn = min(mn, (unsigned)__shfl_xor((int)mn, 4));
          mn = min(mn, (unsigned)__shfl_xor((int)mn, 8));
          win[rnd] = mn;
#pragma unroll
          for (int n = 0; n < 8; ++n)
            if (keys[n] == mn) keys[n] = 0xFFFFFFFFu;
        }
        if (col == 0) {
          int token = m * 16 + quad * 4 + r;
          unsigned* cp = &cands[token][chunk * 12 + wv * 3];
          cp[0] = win[0];
          cp[1] = win[1];
          cp[2] = win[2];
        }
      }
    }
  }
  __syncthreads();

  if (tid < 32) {
    unsigned best[6];
#pragma unroll
    for (int j = 0; j < 6; ++j) best[j] = 0xFFFFFFFFu;
    for (int s = 0; s < 48; ++s) {
      unsigned v = cands[tid][s];
      if (v < best[5]) {
        best[5] = v;
#pragma unroll
        for (int j = 5; j > 0; --j) {
          if (best[j] < best[j - 1]) {
            unsigned t = best[j];
            best[j] = best[j - 1];
            best[j - 1] = t;
          }
        }
      }
    }
#pragma unroll
    for (int j = 0; j < 6; ++j) rcode[tid][j] = (int)(best[j] & 0x7FFu);
  }
  __syncthreads();

  if (tid < 192) {
    int t = tid / 6;
    int j = tid - t * 6;
    int code = rcode[t][j];
    const float* xr = x + (tok0 + t) * (size_t)C_;
    const float* cr = cb + (size_t)code * C_;
    double s = 0.0;
    for (int c = 0; c < C_; c += 4) {
      float4 xa = *(const float4*)(xr + c);
      float4 ca = *(const float4*)(cr + c);
      s = fma((double)xa.x, (double)ca.x, s);
      s = fma((double)xa.y, (double)ca.y, s);
      s = fma((double)xa.z, (double)ca.z, s);
      s = fma((double)xa.w, (double)ca.w, s);
    }
    rd[t][j] = fma(-2.0, s, norms64[code]);
  }
  __syncthreads();

  if (tid < 32) {
    double bv = rd[tid][0];
    int bi = rcode[tid][0];
#pragma unroll
    for (int j = 1; j < 6; ++j) {
      double v = rd[tid][j];
      int i0 = rcode[tid][j];
      if (v < bv || (v == bv && i0 < bi)) {
        bv = v;
        bi = i0;
      }
    }
    out_idx[tok0 + tid] = bi;
  }
}

// ---------------------------------------------------------------------------
// Kernel E: per-batch softmax over att = ac[idx[l]] + fused output.
// 1024 threads (16 waves/CU) to hide the cb-gather latency.
// ---------------------------------------------------------------------------
__global__ __launch_bounds__(1024) void epilogue_kernel(
    const float* __restrict__ x, const float* __restrict__ cb,
    const float* __restrict__ ac, const int* __restrict__ idx,
    float* __restrict__ out, float* __restrict__ out_idx) {
  __shared__ float att[256];
  __shared__ float red[256];
  __shared__ int ids[L_];
  int b = blockIdx.x;
  int tid = threadIdx.x;

  float e = 0.0f;
  if (tid < 256) {
    float a = -1e30f;
    if (tid < L_) {
      int myid = idx[b * L_ + tid];
      ids[tid] = myid;
      a = ac[myid];
    }
    att[tid] = a;
    red[tid] = a;
  }
  __syncthreads();
  for (int s = 128; s > 0; s >>= 1) {
    if (tid < s) red[tid] = fmaxf(red[tid], red[tid + s]);
    __syncthreads();
  }
  float mx = red[0];
  __syncthreads();
  if (tid < 256) {
    e = (tid < L_) ? expf(att[tid] - mx) : 0.0f;
    red[tid] = e;
  }
  __syncthreads();
  for (int s = 128; s > 0; s >>= 1) {
    if (tid < s) red[tid] += red[tid + s];
    __syncthreads();
  }
  float sum = red[0];
  __syncthreads();
  if (tid < 256) att[tid] = e / sum;
  __syncthreads();

  const float4* xin = (const float4*)(x + (size_t)b * L_ * C_);
  float4* o = (float4*)(out + (size_t)b * L_ * C_);
  for (int i = tid; i < L_ * (C_ / 4); i += 1024) {
    int l = i / (C_ / 4);
    int c4 = i - l * (C_ / 4);
    const float4* crow = (const float4*)(cb + (size_t)ids[l] * C_);
    float4 xv = xin[i];
    float4 cv = crow[c4];
    float mk = att[l];
    float4 ov;
    ov.x = cv.x + xv.x * mk;
    ov.y = cv.y + xv.y * mk;
    ov.z = cv.z + xv.z * mk;
    ov.w = cv.w + xv.w * mk;
    o[i] = ov;
  }
  if (tid < L_) out_idx[b * L_ + tid] = (float)ids[tid];
}

// ---------------------------------------------------------------------------
extern "C" void kernel_launch(void* const* d_in, const int* in_sizes, int n_in,
                              void* d_out, int out_size, void* d_ws,
                              size_t ws_size, hipStream_t stream) {
  const float* in_feas = (const float*)d_in[0];   // [B,L,C] f32
  const float* cb = (const float*)d_in[1];        // [K,C]   f32
  const float* attw = (const float*)d_in[2];      // [1,C,3] f32

  // workspace layout
  char* ws = (char*)d_ws;
  size_t off = 0;
  unsigned short* cbb = (unsigned short*)(ws + off); off += 3145728;
  double* norms64 = (double*)(ws + off);           off += 16384;
  float* norms32 = (float*)(ws + off);             off += 8192;
  float* ac = (float*)(ws + off);                  off += 8192;
  int* idx = (int*)(ws + off);                     off += 200704;
  size_t base = off;                                // 3,379,200
  unsigned short* xb = (unsigned short*)(ws + off); off += (size_t)BL_ * C_ * 2;
  unsigned* ws_cand = (unsigned*)(ws + off);        off += (size_t)BL_ * 96 * 4;
  size_t need_full = off;                           // ~99.7 MB

  float* out = (float*)d_out;                      // out_feas [B,L,C]
  float* out_idx = out + (size_t)B_ * L_ * C_;     // idx map as float [B,H,W]

  precompute_kernel<<<K_ / 4, 256, 0, stream>>>(cb, attw, cbb, norms64,
                                                norms32, ac);
  if (ws_size >= need_full) {
    convert_kernel<<<BL_ * C_ / 4 / 256, 256, 0, stream>>>(in_feas, xb);
    // 1568 blocks = (BL/256) * (K/256) = 196 * 8
    phase1_kernel<<<dim3((BL_ / 256) * (K_ / 256)), 512, 0, stream>>>(
        xb, cbb, norms32, ws_cand);
    phase2_kernel<<<BL_ / 32, 256, 0, stream>>>(in_feas, cb, ws_cand, norms64,
                                                idx);
  } else {
    argmin_fallback<<<BL_ / 32, 256, 0, stream>>>(in_feas, cb, cbb, norms64,
                                                  norms32, idx);
  }
  epilogue_kernel<<<B_, 1024, 0, stream>>>(in_feas, cb, ac, idx, out, out_idx);
  (void)base;
}

// Round 4
// 777.902 us; speedup vs baseline: 1.0347x; 1.0238x over previous
//
#include <hip/hip_runtime.h>

// Problem constants
#define B_ 256
#define L_ 196
#define C_ 768
#define K_ 2048
#define BL_ 50176  // B_*L_

typedef __attribute__((ext_vector_type(8))) short bf16x8;
typedef __attribute__((ext_vector_type(4))) float f32x4;

typedef const __attribute__((address_space(1))) void gas_void;
typedef __attribute__((address_space(3))) void las_void;

__device__ __forceinline__ unsigned short f2bf(float f) {
  unsigned u = __builtin_bit_cast(unsigned, f);
  u = u + 0x7FFFu + ((u >> 16) & 1u);  // RNE, no NaN inputs
  return (unsigned short)(u >> 16);
}

// monotone map: float bits -> unsigned with total order (handles negatives)
__device__ __forceinline__ unsigned fmono(float f) {
  unsigned u = __builtin_bit_cast(unsigned, f);
  return u ^ ((unsigned)((int)u >> 31) | 0x80000000u);
}

// ---------------------------------------------------------------------------
// Kernel P: per-code precompute: cbb bf16 [K][C], norms64/32, ac.
// ---------------------------------------------------------------------------
__global__ __launch_bounds__(256) void precompute_kernel(
    const float* __restrict__ cb, const float* __restrict__ attw,
    unsigned short* __restrict__ cbb, double* __restrict__ norms64,
    float* __restrict__ norms32, float* __restrict__ ac) {
  int wave = threadIdx.x >> 6;
  int lane = threadIdx.x & 63;
  int k = blockIdx.x * 4 + wave;
  const float* row = cb + (size_t)k * C_;
  double n = 0.0, a = 0.0;
  for (int c = lane; c < C_; c += 64) {
    float v = row[c];
    cbb[(size_t)k * C_ + c] = f2bf(v);
    n = fma((double)v, (double)v, n);
    a = fma((double)v, (double)attw[c * 3 + 1], a);
  }
  for (int off = 32; off > 0; off >>= 1) {
    n += __shfl_down(n, off);
    a += __shfl_down(a, off);
  }
  if (lane == 0) {
    norms64[k] = n;
    norms32[k] = (float)n;
    ac[k] = (a > 0.0) ? (float)a : 0.0f;
  }
}

// ---------------------------------------------------------------------------
// Kernel X: convert in_feas f32 -> bf16 xb [BL][C]. 9633792 float4 groups.
// ---------------------------------------------------------------------------
__global__ __launch_bounds__(256) void convert_kernel(
    const float* __restrict__ x, unsigned short* __restrict__ xb) {
  int i = blockIdx.x * 256 + threadIdx.x;  // exact: 37632*256 = BL_*C_/4
  float4 v = ((const float4*)x)[i];
  uint2 w;
  w.x = (unsigned)f2bf(v.x) | ((unsigned)f2bf(v.y) << 16);
  w.y = (unsigned)f2bf(v.z) | ((unsigned)f2bf(v.w) << 16);
  ((uint2*)xb)[i] = w;
}

// ---------------------------------------------------------------------------
// Phase 1 (v4): 256x256 tile, BK=64, 512 threads = 8 waves (2M x 4N).
// 3-barrier-per-K-tile pipelined schedule with counted vmcnt (no drain):
// barriers ONLY protect buffer transitions -- lanes never ds_write (staging
// is DMA) and tile t's DMA targets buffer t+1 exclusively, so quadrant
// phases within a tile need no lockstep. Per-wave ds_read->MFMA waits are
// compiler-managed (fine-grained lgkmcnt), letting waves slip so ds_read of
// one wave overlaps MFMA of another (m97-style CU-level overlap) while the
// counted vmcnt keeps staging loads in flight across barriers (T4).
// Steady-state ledger (2 loads per stage; issue order per tile:
// A0,B0 @P0; B1 @P1; A1 @P2):
//   entering t: outstanding {B1(t),A1(t)}; P0 stages A0B0(t+1) -> 8;
//   vmcnt(6) retires B1(t); P1 stages B1(t+1) -> 8; vmcnt(6) retires A1(t);
//   P2 stages A1(t+1) -> 8; boundary vmcnt(4) retires A0B0(t+1).
//   Tail t=11: 2 / 0 / none.
// Block mapping: 8 consecutive blocks on an XCD share mblk across the 8
// code panels -> 384KB xb tile L2-reused 8x; cbb (3MB) L2-resident
// (verified R3: FETCH 312->113 MB).
// ---------------------------------------------------------------------------
__global__ __launch_bounds__(512, 2) void phase1_kernel(
    const unsigned short* __restrict__ xb,
    const unsigned short* __restrict__ cbb,
    const float* __restrict__ norms32, unsigned* __restrict__ ws_cand) {
  // [buf][op(0=A,1=B)][half][128*64] bf16 = 128 KB
  __shared__ unsigned short lds[2][2][2][128 * 64];
  __shared__ float norms_s[256];
  __shared__ unsigned cands_s[256][12];

  int tid = threadIdx.x;
  int bid = blockIdx.x;
  // token-tile-shared-per-XCD mapping (see header comment)
  int x8 = bid & 7, m = bid >> 3;
  int mblk, nblk;
  if (m < 192) {
    mblk = (m & ~7) | x8;  // 8 consecutive blocks on an XCD share mblk
    nblk = m & 7;
  } else {
    mblk = m;  // 192..195
    nblk = x8;
  }
  size_t row0 = (size_t)mblk * 256;
  int code0 = nblk * 256;

  int wv = tid >> 6, l = tid & 63;
  int wm = wv >> 2, wn = wv & 3;  // 2 x 4 wave grid
  int col16 = l & 15, quad = l >> 4;

  if (tid < 256) norms_s[tid] = norms32[code0 + tid];

  // staging geometry: half-tile = 128 rows x 64 cols bf16 = 16 KB.
  // chunk c = i*512 + tid -> LDS byte c*16; row = i*64 + (tid>>3),
  // slotpos = tid&7; source slot XOR-swizzled: slotraw = slotpos ^ (row&7).
  int slotraw = (tid & 7) ^ ((tid >> 3) & 7);
  const unsigned short* abase = xb + (row0 + (tid >> 3)) * (size_t)C_ +
                                (size_t)slotraw * 8;
  const unsigned short* bbase = cbb + ((size_t)code0 + (tid >> 3)) * C_ +
                                (size_t)slotraw * 8;

  auto stageA = [&](int kt, int half, int buf) {
    const unsigned short* s =
        abase + (size_t)half * 128 * C_ + (size_t)kt * 64;
    char* d = (char*)&lds[buf][0][half][0] + wv * 1024;
    __builtin_amdgcn_global_load_lds((gas_void*)s, (las_void*)d, 16, 0, 0);
    __builtin_amdgcn_global_load_lds((gas_void*)(s + (size_t)64 * C_),
                                     (las_void*)(d + 8192), 16, 0, 0);
  };
  auto stageB = [&](int kt, int half, int buf) {
    const unsigned short* s =
        bbase + (size_t)half * 128 * C_ + (size_t)kt * 64;
    char* d = (char*)&lds[buf][1][half][0] + wv * 1024;
    __builtin_amdgcn_global_load_lds((gas_void*)s, (las_void*)d, 16, 0, 0);
    __builtin_amdgcn_global_load_lds((gas_void*)(s + (size_t)64 * C_),
                                     (las_void*)(d + 8192), 16, 0, 0);
  };

  f32x4 acc[2][2][4][2];  // [mh][nh][mt][nt]
#pragma unroll
  for (int mh = 0; mh < 2; ++mh)
#pragma unroll
    for (int nh = 0; nh < 2; ++nh)
#pragma unroll
      for (int mt = 0; mt < 4; ++mt)
#pragma unroll
        for (int nt = 0; nt < 2; ++nt)
          acc[mh][nh][mt][nt] = (f32x4){0.f, 0.f, 0.f, 0.f};

  bf16x8 af[4][2], bfr[2][2];

#define LOADA(P)                                                            \
  _Pragma("unroll") for (int mt = 0; mt < 4; ++mt)                          \
      _Pragma("unroll") for (int ks = 0; ks < 2; ++ks) af[mt][ks] =         \
      *(const bf16x8*)((P) + (wm * 64 + mt * 16 + col16) * 128 +            \
                       (((ks * 4 + quad) ^ (col16 & 7)) * 16));

#define LOADB(P)                                                            \
  _Pragma("unroll") for (int nt = 0; nt < 2; ++nt)                          \
      _Pragma("unroll") for (int ks = 0; ks < 2; ++ks) bfr[nt][ks] =        \
      *(const bf16x8*)((P) + (wn * 32 + nt * 16 + col16) * 128 +            \
                       (((ks * 4 + quad) ^ (col16 & 7)) * 16));

#define MFMA_Q(mh, nh)                                                      \
  __builtin_amdgcn_s_setprio(1);                                            \
  _Pragma("unroll") for (int mt = 0; mt < 4; ++mt)                          \
      _Pragma("unroll") for (int nt = 0; nt < 2; ++nt)                      \
          _Pragma("unroll") for (int ks = 0; ks < 2; ++ks) acc[mh][nh][mt]  \
      [nt] = __builtin_amdgcn_mfma_f32_16x16x32_bf16(                       \
          af[mt][ks], bfr[nt][ks], acc[mh][nh][mt][nt], 0, 0, 0);           \
  __builtin_amdgcn_s_setprio(0);

  // Prologue: stage all 4 halves of tile 0 (order A0,B0,B1,A1), then match
  // the steady-state entry condition: A0,B0 retired, {B1,A1} in flight.
  stageA(0, 0, 0);
  stageB(0, 0, 0);
  stageB(0, 1, 0);
  stageA(0, 1, 0);
  asm volatile("s_waitcnt vmcnt(4)" ::: "memory");
  __builtin_amdgcn_s_barrier();

  for (int t = 0; t < 12; ++t) {
    int buf = t & 1;
    const char* A0p = (const char*)&lds[buf][0][0][0];
    const char* A1p = (const char*)&lds[buf][0][1][0];
    const char* B0p = (const char*)&lds[buf][1][0][0];
    const char* B1p = (const char*)&lds[buf][1][1][0];
    bool st = (t < 11);

    // ---- P0: quadrant (A0,B0); stage A0,B0 of t+1 into buf^1 ----
    if (st) {
      stageA(t + 1, 0, buf ^ 1);
      stageB(t + 1, 0, buf ^ 1);
    }
    LOADA(A0p);
    LOADB(B0p);
    MFMA_Q(0, 0);
    if (st) {
      asm volatile("s_waitcnt vmcnt(6)" ::: "memory");  // retire B1(t)
    } else {
      asm volatile("s_waitcnt vmcnt(2)" ::: "memory");
    }
    __builtin_amdgcn_s_barrier();

    // ---- P1: quadrant (A0,B1); stage B1 of t+1 ----
    if (st) stageB(t + 1, 1, buf ^ 1);
    LOADB(B1p);
    MFMA_Q(0, 1);
    if (st) {
      asm volatile("s_waitcnt vmcnt(6)" ::: "memory");  // retire A1(t)
    } else {
      asm volatile("s_waitcnt vmcnt(0)" ::: "memory");
    }
    __builtin_amdgcn_s_barrier();

    // ---- P2+P3 merged (no barrier between): (A1,B1) then (A1,B0) ----
    if (st) stageA(t + 1, 1, buf ^ 1);
    LOADA(A1p);
    MFMA_Q(1, 1);
    LOADB(B0p);
    MFMA_Q(1, 0);
    if (st) {
      asm volatile("s_waitcnt vmcnt(4)" ::: "memory");  // retire A0B0(t+1)
    }
    __builtin_amdgcn_s_barrier();  // boundary: buf free for t+2's DMA
  }

#undef LOADA
#undef LOADB
#undef MFMA_Q

  // epilogue: top-3 per token within this wave's 64 codes (4x16 over nh,nt)
#pragma unroll
  for (int mh = 0; mh < 2; ++mh) {
#pragma unroll
    for (int mt = 0; mt < 4; ++mt) {
#pragma unroll
      for (int r = 0; r < 4; ++r) {
        unsigned keys[4];
#pragma unroll
        for (int nh = 0; nh < 2; ++nh)
#pragma unroll
          for (int nt = 0; nt < 2; ++nt) {
            int codel = nh * 128 + wn * 32 + nt * 16 + col16;
            float d = fmaf(-2.0f, acc[mh][nh][mt][nt][r], norms_s[codel]);
            keys[nh * 2 + nt] =
                (fmono(d) & 0xFFFFF800u) | (unsigned)(code0 + codel);
          }
        unsigned win[3];
#pragma unroll
        for (int rnd = 0; rnd < 3; ++rnd) {
          unsigned mn = min(min(keys[0], keys[1]), min(keys[2], keys[3]));
          mn = min(mn, (unsigned)__shfl_xor((int)mn, 1));
          mn = min(mn, (unsigned)__shfl_xor((int)mn, 2));
          mn = min(mn, (unsigned)__shfl_xor((int)mn, 4));
          mn = min(mn, (unsigned)__shfl_xor((int)mn, 8));
          win[rnd] = mn;
#pragma unroll
          for (int nt = 0; nt < 4; ++nt)
            if (keys[nt] == mn) keys[nt] = 0xFFFFFFFFu;
        }
        if (col16 == 0) {
          int t = mh * 128 + wm * 64 + mt * 16 + quad * 4 + r;
          cands_s[t][wn * 3 + 0] = win[0];
          cands_s[t][wn * 3 + 1] = win[1];
          cands_s[t][wn * 3 + 2] = win[2];
        }
      }
    }
  }
  __syncthreads();
  for (int i = tid; i < 256 * 12; i += 512) {
    int t = i / 12;
    int j = i - t * 12;
    ws_cand[(row0 + t) * 96 + nblk * 12 + j] = cands_s[t][j];
  }
}

// ---------------------------------------------------------------------------
// Phase 2: per token, top-6 of 96 approx keys -> exact f64 rescore -> idx.
// ---------------------------------------------------------------------------
__global__ __launch_bounds__(256) void phase2_kernel(
    const float* __restrict__ x, const float* __restrict__ cb,
    const unsigned* __restrict__ ws_cand, const double* __restrict__ norms64,
    int* __restrict__ out_idx) {
  __shared__ unsigned cl[32][100];  // pad 96->100 (bank spread)
  __shared__ int rcode[32][6];
  __shared__ double rd[32][6];
  int tid = threadIdx.x;
  size_t tok0 = (size_t)blockIdx.x * 32;

  for (int i = tid; i < 32 * 96; i += 256) {
    int t = i / 96;
    int s = i - t * 96;
    cl[t][s] = ws_cand[tok0 * 96 + i];
  }
  __syncthreads();

  if (tid < 32) {
    unsigned best[6];
#pragma unroll
    for (int j = 0; j < 6; ++j) best[j] = 0xFFFFFFFFu;
    for (int s = 0; s < 96; ++s) {
      unsigned v = cl[tid][s];
      if (v < best[5]) {
        best[5] = v;
#pragma unroll
        for (int j = 5; j > 0; --j) {
          if (best[j] < best[j - 1]) {
            unsigned t = best[j];
            best[j] = best[j - 1];
            best[j - 1] = t;
          }
        }
      }
    }
#pragma unroll
    for (int j = 0; j < 6; ++j) rcode[tid][j] = (int)(best[j] & 0x7FFu);
  }
  __syncthreads();

  if (tid < 192) {
    int t = tid / 6;
    int j = tid - t * 6;
    int code = rcode[t][j];
    const float* xr = x + (tok0 + t) * (size_t)C_;
    const float* cr = cb + (size_t)code * C_;
    double s = 0.0;
    for (int c = 0; c < C_; c += 4) {
      float4 xa = *(const float4*)(xr + c);
      float4 ca = *(const float4*)(cr + c);
      s = fma((double)xa.x, (double)ca.x, s);
      s = fma((double)xa.y, (double)ca.y, s);
      s = fma((double)xa.z, (double)ca.z, s);
      s = fma((double)xa.w, (double)ca.w, s);
    }
    rd[t][j] = fma(-2.0, s, norms64[code]);
  }
  __syncthreads();

  if (tid < 32) {
    double bv = rd[tid][0];
    int bi = rcode[tid][0];
#pragma unroll
    for (int j = 1; j < 6; ++j) {
      double v = rd[tid][j];
      int i0 = rcode[tid][j];
      if (v < bv || (v == bv && i0 < bi)) {
        bv = v;
        bi = i0;
      }
    }
    out_idx[tok0 + tid] = bi;
  }
}

// ---------------------------------------------------------------------------
// Fallback argmin (round-2 kernel) if ws_size is too small for phase 1/2.
// ---------------------------------------------------------------------------
#define APAD 776
__global__ __launch_bounds__(256, 2) void argmin_fallback(
    const float* __restrict__ x, const float* __restrict__ cb,
    const unsigned short* __restrict__ cbb,
    const double* __restrict__ norms64, const float* __restrict__ norms32,
    int* __restrict__ out_idx) {
  __shared__ unsigned short Asf[32 * APAD];
  __shared__ float norms_s[K_];
  __shared__ unsigned int cands[32][48];
  __shared__ int rcode[32][6];
  __shared__ double rd[32][6];

  int tid = threadIdx.x;
  size_t tok0 = (size_t)blockIdx.x * 32;

  for (int i = tid; i < K_; i += 256) norms_s[i] = norms32[i];

  const float4* xin = (const float4*)(x + tok0 * C_);
  for (int i = tid; i < 32 * 192; i += 256) {
    int tok = i / 192;
    int c4 = i - tok * 192;
    float4 v = xin[i];
    uint2 w;
    w.x = (unsigned)f2bf(v.x) | ((unsigned)f2bf(v.y) << 16);
    w.y = (unsigned)f2bf(v.z) | ((unsigned)f2bf(v.w) << 16);
    *(uint2*)&Asf[tok * APAD + c4 * 4] = w;
  }
  __syncthreads();

  int wv = tid >> 6;
  int lane = tid & 63;
  int col = lane & 15;
  int quad = lane >> 4;

  const unsigned short* a0p = &Asf[(col)*APAD + quad * 8];
  const unsigned short* a1p = &Asf[(16 + col) * APAD + quad * 8];

  for (int chunk = 0; chunk < 4; ++chunk) {
    int code0 = chunk * 512 + wv * 128 + col;
    const unsigned short* bbase = cbb + (size_t)code0 * C_ + quad * 8;

    f32x4 acc[2][8];
#pragma unroll
    for (int m = 0; m < 2; ++m)
#pragma unroll
      for (int n = 0; n < 8; ++n) acc[m][n] = (f32x4){0.f, 0.f, 0.f, 0.f};

    bf16x8 ca0 = *(const bf16x8*)(a0p);
    bf16x8 ca1 = *(const bf16x8*)(a1p);
    bf16x8 cbf[8];
#pragma unroll
    for (int n = 0; n < 8; ++n)
      cbf[n] = *(const bf16x8*)(bbase + (size_t)n * 16 * C_);

    for (int ks = 0; ks < 24; ++ks) {
      bf16x8 na0, na1, nbf[8];
      if (ks < 23) {
        int k1 = (ks + 1) * 32;
        na0 = *(const bf16x8*)(a0p + k1);
        na1 = *(const bf16x8*)(a1p + k1);
#pragma unroll
        for (int n = 0; n < 8; ++n)
          nbf[n] = *(const bf16x8*)(bbase + (size_t)n * 16 * C_ + k1);
      }
#pragma unroll
      for (int n = 0; n < 8; ++n) {
        acc[0][n] = __builtin_amdgcn_mfma_f32_16x16x32_bf16(ca0, cbf[n],
                                                            acc[0][n], 0, 0, 0);
        acc[1][n] = __builtin_amdgcn_mfma_f32_16x16x32_bf16(ca1, cbf[n],
                                                            acc[1][n], 0, 0, 0);
      }
      if (ks < 23) {
        ca0 = na0;
        ca1 = na1;
#pragma unroll
        for (int n = 0; n < 8; ++n) cbf[n] = nbf[n];
      }
    }

#pragma unroll
    for (int m = 0; m < 2; ++m) {
#pragma unroll
      for (int r = 0; r < 4; ++r) {
        unsigned keys[8];
#pragma unroll
        for (int n = 0; n < 8; ++n) {
          int code = code0 + n * 16;
          float d = fmaf(-2.0f, acc[m][n][r], norms_s[code]);
          keys[n] = (fmono(d) & 0xFFFFF800u) | (unsigned)code;
        }
        unsigned win[3];
#pragma unroll
        for (int rnd = 0; rnd < 3; ++rnd) {
          unsigned mn = keys[0];
#pragma unroll
          for (int n = 1; n < 8; ++n) mn = min(mn, keys[n]);
          mn = min(mn, (unsigned)__shfl_xor((int)mn, 1));
          mn = min(mn, (unsigned)__shfl_xor((int)mn, 2));
          mn = min(mn, (unsigned)__shfl_xor((int)mn, 4));
          mn = min(mn, (unsigned)__shfl_xor((int)mn, 8));
          win[rnd] = mn;
#pragma unroll
          for (int n = 0; n < 8; ++n)
            if (keys[n] == mn) keys[n] = 0xFFFFFFFFu;
        }
        if (col == 0) {
          int token = m * 16 + quad * 4 + r;
          unsigned* cp = &cands[token][chunk * 12 + wv * 3];
          cp[0] = win[0];
          cp[1] = win[1];
          cp[2] = win[2];
        }
      }
    }
  }
  __syncthreads();

  if (tid < 32) {
    unsigned best[6];
#pragma unroll
    for (int j = 0; j < 6; ++j) best[j] = 0xFFFFFFFFu;
    for (int s = 0; s < 48; ++s) {
      unsigned v = cands[tid][s];
      if (v < best[5]) {
        best[5] = v;
#pragma unroll
        for (int j = 5; j > 0; --j) {
          if (best[j] < best[j - 1]) {
            unsigned t = best[j];
            best[j] = best[j - 1];
            best[j - 1] = t;
          }
        }
      }
    }
#pragma unroll
    for (int j = 0; j < 6; ++j) rcode[tid][j] = (int)(best[j] & 0x7FFu);
  }
  __syncthreads();

  if (tid < 192) {
    int t = tid / 6;
    int j = tid - t * 6;
    int code = rcode[t][j];
    const float* xr = x + (tok0 + t) * (size_t)C_;
    const float* cr = cb + (size_t)code * C_;
    double s = 0.0;
    for (int c = 0; c < C_; c += 4) {
      float4 xa = *(const float4*)(xr + c);
      float4 ca = *(const float4*)(cr + c);
      s = fma((double)xa.x, (double)ca.x, s);
      s = fma((double)xa.y, (double)ca.y, s);
      s = fma((double)xa.z, (double)ca.z, s);
      s = fma((double)xa.w, (double)ca.w, s);
    }
    rd[t][j] = fma(-2.0, s, norms64[code]);
  }
  __syncthreads();

  if (tid < 32) {
    double bv = rd[tid][0];
    int bi = rcode[tid][0];
#pragma unroll
    for (int j = 1; j < 6; ++j) {
      double v = rd[tid][j];
      int i0 = rcode[tid][j];
      if (v < bv || (v == bv && i0 < bi)) {
        bv = v;
        bi = i0;
      }
    }
    out_idx[tok0 + tid] = bi;
  }
}

// ---------------------------------------------------------------------------
// Kernel E: per-batch softmax over att = ac[idx[l]] + fused output.
// 1024 threads (16 waves/CU) to hide the cb-gather latency.
// ---------------------------------------------------------------------------
__global__ __launch_bounds__(1024) void epilogue_kernel(
    const float* __restrict__ x, const float* __restrict__ cb,
    const float* __restrict__ ac, const int* __restrict__ idx,
    float* __restrict__ out, float* __restrict__ out_idx) {
  __shared__ float att[256];
  __shared__ float red[256];
  __shared__ int ids[L_];
  int b = blockIdx.x;
  int tid = threadIdx.x;

  float e = 0.0f;
  if (tid < 256) {
    float a = -1e30f;
    if (tid < L_) {
      int myid = idx[b * L_ + tid];
      ids[tid] = myid;
      a = ac[myid];
    }
    att[tid] = a;
    red[tid] = a;
  }
  __syncthreads();
  for (int s = 128; s > 0; s >>= 1) {
    if (tid < s) red[tid] = fmaxf(red[tid], red[tid + s]);
    __syncthreads();
  }
  float mx = red[0];
  __syncthreads();
  if (tid < 256) {
    e = (tid < L_) ? expf(att[tid] - mx) : 0.0f;
    red[tid] = e;
  }
  __syncthreads();
  for (int s = 128; s > 0; s >>= 1) {
    if (tid < s) red[tid] += red[tid + s];
    __syncthreads();
  }
  float sum = red[0];
  __syncthreads();
  if (tid < 256) att[tid] = e / sum;
  __syncthreads();

  const float4* xin = (const float4*)(x + (size_t)b * L_ * C_);
  float4* o = (float4*)(out + (size_t)b * L_ * C_);
  for (int i = tid; i < L_ * (C_ / 4); i += 1024) {
    int l = i / (C_ / 4);
    int c4 = i - l * (C_ / 4);
    const float4* crow = (const float4*)(cb + (size_t)ids[l] * C_);
    float4 xv = xin[i];
    float4 cv = crow[c4];
    float mk = att[l];
    float4 ov;
    ov.x = cv.x + xv.x * mk;
    ov.y = cv.y + xv.y * mk;
    ov.z = cv.z + xv.z * mk;
    ov.w = cv.w + xv.w * mk;
    o[i] = ov;
  }
  if (tid < L_) out_idx[b * L_ + tid] = (float)ids[tid];
}

// ---------------------------------------------------------------------------
extern "C" void kernel_launch(void* const* d_in, const int* in_sizes, int n_in,
                              void* d_out, int out_size, void* d_ws,
                              size_t ws_size, hipStream_t stream) {
  const float* in_feas = (const float*)d_in[0];   // [B,L,C] f32
  const float* cb = (const float*)d_in[1];        // [K,C]   f32
  const float* attw = (const float*)d_in[2];      // [1,C,3] f32

  // workspace layout
  char* ws = (char*)d_ws;
  size_t off = 0;
  unsigned short* cbb = (unsigned short*)(ws + off); off += 3145728;
  double* norms64 = (double*)(ws + off);           off += 16384;
  float* norms32 = (float*)(ws + off);             off += 8192;
  float* ac = (float*)(ws + off);                  off += 8192;
  int* idx = (int*)(ws + off);                     off += 200704;
  size_t base = off;                                // 3,379,200
  unsigned short* xb = (unsigned short*)(ws + off); off += (size_t)BL_ * C_ * 2;
  unsigned* ws_cand = (unsigned*)(ws + off);        off += (size_t)BL_ * 96 * 4;
  size_t need_full = off;                           // ~99.7 MB

  float* out = (float*)d_out;                      // out_feas [B,L,C]
  float* out_idx = out + (size_t)B_ * L_ * C_;     // idx map as float [B,H,W]

  precompute_kernel<<<K_ / 4, 256, 0, stream>>>(cb, attw, cbb, norms64,
                                                norms32, ac);
  if (ws_size >= need_full) {
    convert_kernel<<<BL_ * C_ / 4 / 256, 256, 0, stream>>>(in_feas, xb);
    // 1568 blocks = (BL/256) * (K/256) = 196 * 8
    phase1_kernel<<<dim3((BL_ / 256) * (K_ / 256)), 512, 0, stream>>>(
        xb, cbb, norms32, ws_cand);
    phase2_kernel<<<BL_ / 32, 256, 0, stream>>>(in_feas, cb, ws_cand, norms64,
                                                idx);
  } else {
    argmin_fallback<<<BL_ / 32, 256, 0, stream>>>(in_feas, cb, cbb, norms64,
                                                  norms32, idx);
  }
  epilogue_kernel<<<B_, 1024, 0, stream>>>(in_feas, cb, ac, idx, out, out_idx);
  (void)base;
}